// Round 1
// 1641.770 us; speedup vs baseline: 1.1866x; 1.1866x over previous
//
#include <hip/hip_runtime.h>
#include <stdint.h>

#define TOKENS 8192
#define OUT_F  16384
#define IN_F   4096

typedef short bf16x8 __attribute__((ext_vector_type(8)));
typedef float f32x4  __attribute__((ext_vector_type(4)));

__device__ __forceinline__ unsigned short bf16_rne(float f) {
    union { float f; unsigned int u; } v; v.f = f;
    unsigned int u = v.u;
    u += 0x7fffu + ((u >> 16) & 1u);   // round-to-nearest-even (finite inputs)
    return (unsigned short)(u >> 16);
}

__device__ __forceinline__ unsigned int pack_bf16x2(float a, float b) {
    return (unsigned int)bf16_rne(a) | ((unsigned int)bf16_rne(b) << 16);
}

// async global->LDS DMA, 16B/lane. LDS dst is wave-uniform base + lane*16.
__device__ __forceinline__ void async_cp16(const void* gptr, void* ldsptr) {
    __builtin_amdgcn_global_load_lds(
        (const __attribute__((address_space(1))) unsigned int*)gptr,
        (__attribute__((address_space(3))) unsigned int*)ldsptr,
        16, 0, 0);
}

// ---------------- pre-pass 1: x fp32 -> bf16 ----------------
__global__ __launch_bounds__(256) void cvt_input_kernel(
    const float* __restrict__ in, unsigned short* __restrict__ out, int n8)
{
    int i = blockIdx.x * 256 + threadIdx.x;
    if (i >= n8) return;
    size_t base = (size_t)i * 8;
    float4 a = *(const float4*)(in + base);
    float4 b = *(const float4*)(in + base + 4);
    uint4 p;
    p.x = pack_bf16x2(a.x, a.y);  p.y = pack_bf16x2(a.z, a.w);
    p.z = pack_bf16x2(b.x, b.y);  p.w = pack_bf16x2(b.z, b.w);
    *(uint4*)(out + base) = p;
}

// ---------------- pre-pass 2: idx -> bf16(LUT[idx]) ----------------
__global__ __launch_bounds__(256) void dequant_kernel(
    const int* __restrict__ idx, const float* __restrict__ lut,
    unsigned short* __restrict__ out, int n8)
{
    __shared__ float slut[256];
    slut[threadIdx.x] = lut[threadIdx.x];
    __syncthreads();
    int i = blockIdx.x * 256 + threadIdx.x;
    if (i >= n8) return;
    size_t base = (size_t)i * 8;
    int4 i0 = *(const int4*)(idx + base);
    int4 i1 = *(const int4*)(idx + base + 4);
    uint4 p;
    p.x = pack_bf16x2(slut[i0.x], slut[i0.y]);
    p.y = pack_bf16x2(slut[i0.z], slut[i0.w]);
    p.z = pack_bf16x2(slut[i1.x], slut[i1.y]);
    p.w = pack_bf16x2(slut[i1.z], slut[i1.w]);
    *(uint4*)(out + base) = p;
}

// ================= 256x256 8-phase GEMM (m201-style template) =================
// C[M,N] = A[M,K] * B[N,K]^T + bias.  BM=BN=256, BK=64, 8 waves (2M x 4N),
// LDS 128 KiB = 2 buffers x (A[2x128x64] + B[2x128x64]) bf16.
// Per buffer byte map: A0=0, A1=16384, B0=32768, B1=49152.  buf1 base = 65536.
// LDS swizzle (T2): phys = logical ^ (((logical>>7)&7)<<4) — involution, 16B-granular,
// applied as pre-swizzled global SOURCE for global_load_lds (linear dest) and
// as XOR on the ds_read column offset.
__global__ __launch_bounds__(512, 2) void palett_gemm256(
    const unsigned short* __restrict__ A,   // [TOKENS][IN_F] bf16
    const unsigned short* __restrict__ B,   // [OUT_F][IN_F] bf16
    const float* __restrict__ bias,
    float* __restrict__ out)
{
    __shared__ __align__(16) char sm[131072];

    const int t    = threadIdx.x;
    const int w    = t >> 6;       // wave 0..7
    const int l    = t & 63;
    const int quad = l >> 4;
    const int r16  = l & 15;
    const int wr   = w >> 2;       // wave M row   (0..1) -> 128 rows
    const int wc   = w & 3;        // wave N col   (0..3) -> 64 cols

    // T1: XCD-aware bijective block swizzle (nwg=2048, 2048%8==0)
    const int orig = blockIdx.y * gridDim.x + blockIdx.x;   // 0..2047
    const int swzb = (orig & 7) * 256 + (orig >> 3);
    const int n0   = (swzb & 63) << 8;
    const int m0   = (swzb >> 6) << 8;

    // staging source (pre-swizzled): lane covers row srow (+8 for 2nd load),
    // 16B chunk at swizzled column ((l&7)^(l>>3))*8 elems.
    const int srow = w * 16 + (l >> 3);              // 0..127 within half
    const int scol = ((l & 7) ^ (l >> 3)) << 3;      // elems
    const unsigned short* pA = A + (size_t)(m0 + srow) * IN_F + scol;
    const unsigned short* pB = B + (size_t)(n0 + srow) * IN_F + scol;

    // ds_read byte-offset components (XOR-swizzled columns)
    const int cswz  = (r16 & 7) << 4;
    const int col0  = (quad * 16) ^ cswz;            // kk=0
    const int col1  = (64 + quad * 16) ^ cswz;       // kk=1
    const int arow  = r16 * 128;
    const int abase = wr * 16384;                            // this wave's A half
    const int bbase = 32768 + (wc >> 1) * 16384 + (wc & 1) * 8192; // B half + sub

    f32x4  acc[8][4] = {};
    bf16x8 rA[4][2], rB0[2][2], rB1[2][2];

#define BARRIER() asm volatile("s_barrier" ::: "memory")

#define STAGE(P, HOFF, LOFF, KOFF) do {                                          \
    async_cp16((P) + (size_t)(HOFF) * IN_F + (KOFF), sm + (LOFF) + w * 2048);    \
    async_cp16((P) + (size_t)((HOFF) + 8) * IN_F + (KOFF),                       \
               sm + (LOFF) + w * 2048 + 1024);                                   \
} while (0)

#define READ_A(RB_, MH) do {                                                     \
    _Pragma("unroll")                                                            \
    for (int i_ = 0; i_ < 4; ++i_) {                                             \
        rA[i_][0] = *(const bf16x8*)(sm + (RB_) + abase + ((MH)*4 + i_)*2048 + arow + col0); \
        rA[i_][1] = *(const bf16x8*)(sm + (RB_) + abase + ((MH)*4 + i_)*2048 + arow + col1); \
    }                                                                            \
} while (0)

#define READ_B(DST, RB_, NH) do {                                                \
    _Pragma("unroll")                                                            \
    for (int j_ = 0; j_ < 2; ++j_) {                                             \
        DST[j_][0] = *(const bf16x8*)(sm + (RB_) + bbase + ((NH)*2 + j_)*2048 + arow + col0); \
        DST[j_][1] = *(const bf16x8*)(sm + (RB_) + bbase + ((NH)*2 + j_)*2048 + arow + col1); \
    }                                                                            \
} while (0)

#define MFMA_Q(MH, NH, RB) do {                                                  \
    _Pragma("unroll")                                                            \
    for (int i_ = 0; i_ < 4; ++i_) {                                             \
        _Pragma("unroll")                                                        \
        for (int j_ = 0; j_ < 2; ++j_) {                                         \
            acc[(MH)*4+i_][(NH)*2+j_] = __builtin_amdgcn_mfma_f32_16x16x32_bf16( \
                rA[i_][0], RB[j_][0], acc[(MH)*4+i_][(NH)*2+j_], 0, 0, 0);       \
            acc[(MH)*4+i_][(NH)*2+j_] = __builtin_amdgcn_mfma_f32_16x16x32_bf16( \
                rA[i_][1], RB[j_][1], acc[(MH)*4+i_][(NH)*2+j_], 0, 0, 0);       \
        }                                                                        \
    }                                                                            \
} while (0)

// One K-tile: read from RB_, stage NEXT tile's 4 half-tiles into WB_ (one per
// phase, 2 loads each).  Gate (P1): vmcnt(2) keeps only this phase's 2 fresh
// loads in flight -> all 8 loads of THIS tile (issued last tile) have landed;
// s_barrier then certifies across waves.  No other vmcnt in the loop (T4).
#define TILE(RB_, WB_, KOFF) do {                                                \
    /* P1: gate, read A(lo)+B, Q00 */                                            \
    STAGE(pA, 0, (WB_) + 0, KOFF);                                               \
    asm volatile("s_waitcnt vmcnt(2)" ::: "memory");                             \
    BARRIER();                                                                   \
    READ_A(RB_, 0);                                                              \
    READ_B(rB0, RB_, 0);                                                         \
    __builtin_amdgcn_s_setprio(1);                                               \
    MFMA_Q(0, 0, rB0);                                                           \
    __builtin_amdgcn_s_setprio(0);                                               \
    READ_B(rB1, RB_, 1);                                                         \
    BARRIER();                                                                   \
    /* P2: Q01, prefetch-read A(hi) under next barrier */                        \
    STAGE(pA, 128, (WB_) + 16384, KOFF);                                         \
    BARRIER();                                                                   \
    __builtin_amdgcn_s_setprio(1);                                               \
    MFMA_Q(0, 1, rB1);                                                           \
    __builtin_amdgcn_s_setprio(0);                                               \
    READ_A(RB_, 1);                                                              \
    BARRIER();                                                                   \
    /* P3: Q10 */                                                                \
    STAGE(pB, 0, (WB_) + 32768, KOFF);                                           \
    BARRIER();                                                                   \
    __builtin_amdgcn_s_setprio(1);                                               \
    MFMA_Q(1, 0, rB0);                                                           \
    __builtin_amdgcn_s_setprio(0);                                               \
    BARRIER();                                                                   \
    /* P4: Q11 */                                                                \
    STAGE(pB, 128, (WB_) + 49152, KOFF);                                         \
    BARRIER();                                                                   \
    __builtin_amdgcn_s_setprio(1);                                               \
    MFMA_Q(1, 1, rB1);                                                           \
    __builtin_amdgcn_s_setprio(0);                                               \
    BARRIER();                                                                   \
} while (0)

    // prologue: stage tile 0 into buf0 (8 loads/wave)
    STAGE(pA, 0,   0,     0);
    STAGE(pA, 128, 16384, 0);
    STAGE(pB, 0,   32768, 0);
    STAGE(pB, 128, 49152, 0);

#pragma unroll 1
    for (int it = 0; it < 32; ++it) {
        const int k1 = (2 * it + 1) * 64;            // staged during even tile
        const int k2 = ((2 * it + 2) & 63) * 64;     // staged during odd tile (wraps on last)
        TILE(0,     65536, k1);
        TILE(65536, 0,     k2);
    }
    asm volatile("s_waitcnt vmcnt(0)" ::: "memory"); // drain dangling prefetch

#undef TILE
#undef MFMA_Q
#undef READ_B
#undef READ_A
#undef STAGE
#undef BARRIER

    // epilogue: C/D layout row = quad*4 + v, col = r16
    float bj[4];
#pragma unroll
    for (int j = 0; j < 4; ++j) bj[j] = bias[n0 + wc * 64 + j * 16 + r16];

#pragma unroll
    for (int mf = 0; mf < 8; ++mf) {
        const int mrow = m0 + wr * 128 + mf * 16 + quad * 4;
#pragma unroll
        for (int nf = 0; nf < 4; ++nf) {
            const int n = n0 + wc * 64 + nf * 16 + r16;
#pragma unroll
            for (int v = 0; v < 4; ++v)
                out[(size_t)(mrow + v) * OUT_F + n] = acc[mf][nf][v] + bj[nf];
        }
    }
}

// ---------------- fused fallback (only if workspace too small) ----------------
__global__ __launch_bounds__(256) void palett_gemm_fused(
    const float* __restrict__ Af,             // [M][K] fp32
    const int* __restrict__ Widx,             // [N][K] int32
    const float* __restrict__ lut,
    const float* __restrict__ bias,
    float* __restrict__ out)
{
    __shared__ __align__(16) unsigned short smA[128 * 32];
    __shared__ __align__(16) unsigned short smB[128 * 32];
    __shared__ float slut[256];

    const int t    = threadIdx.x;
    const int w    = t >> 6;
    const int l    = t & 63;
    const int quad = l >> 4;
    const int r16  = l & 15;
    const int wr   = w >> 1;
    const int wc   = w & 1;

    const int m0 = blockIdx.y * 128;
    const int n0 = blockIdx.x * 128;

    const int g0  = t * 8;
    const int row = g0 >> 5;
    const int col = g0 & 31;

    char* const smA_c = (char*)smA;
    char* const smB_c = (char*)smB;

    slut[t] = lut[t];
    __syncthreads();

    uint32_t aoff[4], boff[4];
#pragma unroll
    for (int i = 0; i < 4; ++i) {
        aoff[i] = (uint32_t)(((wr * 64 + i * 16 + r16) * 32 + quad * 8) * 2);
        boff[i] = (uint32_t)(((wc * 64 + i * 16 + r16) * 32 + quad * 8) * 2);
    }

    f32x4 acc[4][4] = {};

    const float* af0 = Af + (size_t)(m0 + row) * IN_F + col;
    const float* af1 = Af + (size_t)(m0 + row + 64) * IN_F + col;
    const int*   wi0 = Widx + (size_t)(n0 + row) * IN_F + col;
    const int*   wi1 = Widx + (size_t)(n0 + row + 64) * IN_F + col;

    for (int k0 = 0; k0 < IN_F; k0 += 32) {
        float4 x0 = *(const float4*)(af0 + k0);
        float4 x1 = *(const float4*)(af0 + k0 + 4);
        uint4 p;
        p.x = pack_bf16x2(x0.x, x0.y); p.y = pack_bf16x2(x0.z, x0.w);
        p.z = pack_bf16x2(x1.x, x1.y); p.w = pack_bf16x2(x1.z, x1.w);
        *(uint4*)(smA_c + t * 16) = p;
        x0 = *(const float4*)(af1 + k0);
        x1 = *(const float4*)(af1 + k0 + 4);
        p.x = pack_bf16x2(x0.x, x0.y); p.y = pack_bf16x2(x0.z, x0.w);
        p.z = pack_bf16x2(x1.x, x1.y); p.w = pack_bf16x2(x1.z, x1.w);
        *(uint4*)(smA_c + 4096 + t * 16) = p;

        int4 j0 = *(const int4*)(wi0 + k0);
        int4 j1 = *(const int4*)(wi0 + k0 + 4);
        p.x = pack_bf16x2(slut[j0.x], slut[j0.y]);
        p.y = pack_bf16x2(slut[j0.z], slut[j0.w]);
        p.z = pack_bf16x2(slut[j1.x], slut[j1.y]);
        p.w = pack_bf16x2(slut[j1.z], slut[j1.w]);
        *(uint4*)(smB_c + t * 16) = p;
        j0 = *(const int4*)(wi1 + k0);
        j1 = *(const int4*)(wi1 + k0 + 4);
        p.x = pack_bf16x2(slut[j0.x], slut[j0.y]);
        p.y = pack_bf16x2(slut[j0.z], slut[j0.w]);
        p.z = pack_bf16x2(slut[j1.x], slut[j1.y]);
        p.w = pack_bf16x2(slut[j1.z], slut[j1.w]);
        *(uint4*)(smB_c + 4096 + t * 16) = p;
        __syncthreads();

        bf16x8 afr[4], bfr[4];
#pragma unroll
        for (int i = 0; i < 4; ++i) afr[i] = *(const bf16x8*)(smA_c + aoff[i]);
#pragma unroll
        for (int j = 0; j < 4; ++j) bfr[j] = *(const bf16x8*)(smB_c + boff[j]);
#pragma unroll
        for (int i = 0; i < 4; ++i)
#pragma unroll
            for (int j = 0; j < 4; ++j)
                acc[i][j] = __builtin_amdgcn_mfma_f32_16x16x32_bf16(
                    afr[i], bfr[j], acc[i][j], 0, 0, 0);
        __syncthreads();
    }

    float bj[4];
#pragma unroll
    for (int j = 0; j < 4; ++j) bj[j] = bias[n0 + wc * 64 + j * 16 + r16];

#pragma unroll
    for (int i = 0; i < 4; ++i) {
        const int mbase = m0 + wr * 64 + i * 16 + quad * 4;
#pragma unroll
        for (int j = 0; j < 4; ++j) {
            const int n = n0 + wc * 64 + j * 16 + r16;
#pragma unroll
            for (int v = 0; v < 4; ++v) {
                out[(size_t)(mbase + v) * OUT_F + n] = acc[i][j][v] + bj[j];
            }
        }
    }
}

extern "C" void kernel_launch(void* const* d_in, const int* in_sizes, int n_in,
                              void* d_out, int out_size, void* d_ws, size_t ws_size,
                              hipStream_t stream) {
    const float* input = (const float*)d_in[0];   // [8192][4096] fp32
    const int*   widx  = (const int*)d_in[1];     // [16384][4096] int32
    const float* lut   = (const float*)d_in[2];   // [256] fp32
    const float* bias  = (const float*)d_in[3];   // [16384] fp32
    float* out = (float*)d_out;                   // [8192][16384] fp32

    const size_t aBytes = (size_t)TOKENS * IN_F * sizeof(unsigned short); //  64 MB
    const size_t bBytes = (size_t)OUT_F  * IN_F * sizeof(unsigned short); // 128 MB

    if (ws_size >= aBytes + bBytes) {
        unsigned short* wsA = (unsigned short*)d_ws;
        unsigned short* wsB = (unsigned short*)((char*)d_ws + aBytes);
        const int nA8 = (TOKENS * IN_F) / 8;
        const int nB8 = (OUT_F  * IN_F) / 8;
        cvt_input_kernel<<<(nA8 + 255) / 256, 256, 0, stream>>>(input, wsA, nA8);
        dequant_kernel<<<(nB8 + 255) / 256, 256, 0, stream>>>(widx, lut, wsB, nB8);
        dim3 grid2(OUT_F / 256, TOKENS / 256);    // (64, 32) = 2048 blocks
        palett_gemm256<<<grid2, 512, 0, stream>>>(wsA, wsB, bias, out);
    } else {
        dim3 grid(OUT_F / 128, TOKENS / 128);
        palett_gemm_fused<<<grid, 256, 0, stream>>>(input, widx, lut, bias, out);
    }
}

// Round 2
// 1579.591 us; speedup vs baseline: 1.2334x; 1.0394x over previous
//
#include <hip/hip_runtime.h>
#include <stdint.h>

#define TOKENS 8192
#define OUT_F  16384
#define IN_F   4096

typedef short bf16x8 __attribute__((ext_vector_type(8)));
typedef float f32x4  __attribute__((ext_vector_type(4)));

__device__ __forceinline__ unsigned short bf16_rne(float f) {
    union { float f; unsigned int u; } v; v.f = f;
    unsigned int u = v.u;
    u += 0x7fffu + ((u >> 16) & 1u);   // round-to-nearest-even (finite inputs)
    return (unsigned short)(u >> 16);
}

__device__ __forceinline__ unsigned int pack_bf16x2(float a, float b) {
    return (unsigned int)bf16_rne(a) | ((unsigned int)bf16_rne(b) << 16);
}

// async global->LDS DMA, 16B/lane. LDS dst is wave-uniform base + lane*16.
__device__ __forceinline__ void async_cp16(const void* gptr, void* ldsptr) {
    __builtin_amdgcn_global_load_lds(
        (const __attribute__((address_space(1))) unsigned int*)gptr,
        (__attribute__((address_space(3))) unsigned int*)ldsptr,
        16, 0, 0);
}

// ---------------- pre-pass 1: x fp32 -> bf16 ----------------
__global__ __launch_bounds__(256) void cvt_input_kernel(
    const float* __restrict__ in, unsigned short* __restrict__ out, int n8)
{
    int i = blockIdx.x * 256 + threadIdx.x;
    if (i >= n8) return;
    size_t base = (size_t)i * 8;
    float4 a = *(const float4*)(in + base);
    float4 b = *(const float4*)(in + base + 4);
    uint4 p;
    p.x = pack_bf16x2(a.x, a.y);  p.y = pack_bf16x2(a.z, a.w);
    p.z = pack_bf16x2(b.x, b.y);  p.w = pack_bf16x2(b.z, b.w);
    *(uint4*)(out + base) = p;
}

// ---------------- pre-pass 2: idx -> bf16(LUT[idx]) ----------------
__global__ __launch_bounds__(256) void dequant_kernel(
    const int* __restrict__ idx, const float* __restrict__ lut,
    unsigned short* __restrict__ out, int n8)
{
    __shared__ float slut[256];
    slut[threadIdx.x] = lut[threadIdx.x];
    __syncthreads();
    int i = blockIdx.x * 256 + threadIdx.x;
    if (i >= n8) return;
    size_t base = (size_t)i * 8;
    int4 i0 = *(const int4*)(idx + base);
    int4 i1 = *(const int4*)(idx + base + 4);
    uint4 p;
    p.x = pack_bf16x2(slut[i0.x], slut[i0.y]);
    p.y = pack_bf16x2(slut[i0.z], slut[i0.w]);
    p.z = pack_bf16x2(slut[i1.x], slut[i1.y]);
    p.w = pack_bf16x2(slut[i1.z], slut[i1.w]);
    *(uint4*)(out + base) = p;
}

// ================= 256x256 GEMM, 4-phase deep-flight schedule =================
// C[M,N] = A[M,K] * B[N,K]^T + bias.  BM=BN=256, BK=64, 8 waves (2M x 4N),
// LDS 128 KiB = 2 buffers x (A[2x128x64] + B[2x128x64]) bf16.
// Per buffer byte map: A0=0, A1=16384, B0=32768, B1=49152.  buf1 base = 65536.
// Stage stream (per wave, 8 loads/tile, 2 per half-tile):
//   P1(t): B-lo,B-hi(t+1) -> W      (flight to gate: 3 phases)
//   P3(t): A-lo,A-hi(t+2) -> R      (flight to gate: 5 phases)
// Legal: all reads from R certified complete by P2(t)'s lgkmcnt(0)+barrier.
// One gate per tile: vmcnt(4) at P4 leaves only A(t+2) in flight -> all of
// tile t+1's 8 loads have landed; barrier certifies across waves.
// LDS swizzle (T2): phys = logical ^ (((logical>>7)&7)<<4) — involution,
// applied as pre-swizzled global SOURCE (linear global_load_lds dest) and as
// XOR on the ds_read column offset.
__global__ __launch_bounds__(512, 2) void palett_gemm256(
    const unsigned short* __restrict__ A,   // [TOKENS][IN_F] bf16
    const unsigned short* __restrict__ B,   // [OUT_F][IN_F] bf16
    const float* __restrict__ bias,
    float* __restrict__ out)
{
    __shared__ __align__(16) char sm[131072];

    const int t    = threadIdx.x;
    const int w    = t >> 6;       // wave 0..7
    const int l    = t & 63;
    const int quad = l >> 4;
    const int r16  = l & 15;
    const int wr   = w >> 2;       // wave M row   (0..1) -> 128 rows
    const int wc   = w & 3;        // wave N col   (0..3) -> 64 cols

    // T1: XCD-aware bijective block swizzle (nwg=2048, 2048%8==0)
    const int orig = blockIdx.y * gridDim.x + blockIdx.x;   // 0..2047
    const int swzb = (orig & 7) * 256 + (orig >> 3);
    const int n0   = (swzb & 63) << 8;
    const int m0   = (swzb >> 6) << 8;

    // staging source (pre-swizzled): lane covers row srow (+8 for 2nd load),
    // 16B chunk at swizzled column ((l&7)^(l>>3))*8 elems.
    const int srow = w * 16 + (l >> 3);              // 0..127 within half
    const int scol = ((l & 7) ^ (l >> 3)) << 3;      // elems
    const unsigned short* pA = A + (size_t)(m0 + srow) * IN_F + scol;
    const unsigned short* pB = B + (size_t)(n0 + srow) * IN_F + scol;

    // ds_read byte-offset components (XOR-swizzled columns)
    const int cswz  = (r16 & 7) << 4;
    const int col0  = (quad * 16) ^ cswz;            // kk=0
    const int col1  = (64 + quad * 16) ^ cswz;       // kk=1
    const int arow  = r16 * 128;
    const int abase = wr * 16384;                            // this wave's A half
    const int bbase = 32768 + (wc >> 1) * 16384 + (wc & 1) * 8192; // B half + sub

    f32x4  acc[8][4] = {};
    bf16x8 rA[4][2], rB0[2][2], rB1[2][2];

#define BARRIER() asm volatile("s_barrier" ::: "memory")

#define STAGE(P, HOFF, LOFF, KOFF) do {                                          \
    async_cp16((P) + (size_t)(HOFF) * IN_F + (KOFF), sm + (LOFF) + w * 2048);    \
    async_cp16((P) + (size_t)((HOFF) + 8) * IN_F + (KOFF),                       \
               sm + (LOFF) + w * 2048 + 1024);                                   \
} while (0)

#define READ_A(RB_, MH) do {                                                     \
    _Pragma("unroll")                                                            \
    for (int i_ = 0; i_ < 4; ++i_) {                                             \
        rA[i_][0] = *(const bf16x8*)(sm + (RB_) + abase + ((MH)*4 + i_)*2048 + arow + col0); \
        rA[i_][1] = *(const bf16x8*)(sm + (RB_) + abase + ((MH)*4 + i_)*2048 + arow + col1); \
    }                                                                            \
} while (0)

#define READ_B(DST, RB_, NH) do {                                                \
    _Pragma("unroll")                                                            \
    for (int j_ = 0; j_ < 2; ++j_) {                                             \
        DST[j_][0] = *(const bf16x8*)(sm + (RB_) + bbase + ((NH)*2 + j_)*2048 + arow + col0); \
        DST[j_][1] = *(const bf16x8*)(sm + (RB_) + bbase + ((NH)*2 + j_)*2048 + arow + col1); \
    }                                                                            \
} while (0)

#define MFMA_Q(MH, NH, RB) do {                                                  \
    _Pragma("unroll")                                                            \
    for (int i_ = 0; i_ < 4; ++i_) {                                             \
        _Pragma("unroll")                                                        \
        for (int j_ = 0; j_ < 2; ++j_) {                                         \
            acc[(MH)*4+i_][(NH)*2+j_] = __builtin_amdgcn_mfma_f32_16x16x32_bf16( \
                rA[i_][0], RB[j_][0], acc[(MH)*4+i_][(NH)*2+j_], 0, 0, 0);       \
            acc[(MH)*4+i_][(NH)*2+j_] = __builtin_amdgcn_mfma_f32_16x16x32_bf16( \
                rA[i_][1], RB[j_][1], acc[(MH)*4+i_][(NH)*2+j_], 0, 0, 0);       \
        }                                                                        \
    }                                                                            \
} while (0)

// KB_ = element k-offset of tile t+1 (B staging), KA_ = k-offset of tile t+2 (A staging)
#define TILE(RB_, WB_, KB_, KA_) do {                                            \
    /* P1: stage B(t+1); read A-lo,B0; Q00 */                                    \
    STAGE(pB, 0,   (WB_) + 32768, KB_);                                          \
    STAGE(pB, 128, (WB_) + 49152, KB_);                                          \
    READ_A(RB_, 0);                                                              \
    READ_B(rB0, RB_, 0);                                                         \
    __builtin_amdgcn_s_setprio(1);                                               \
    MFMA_Q(0, 0, rB0);                                                           \
    __builtin_amdgcn_s_setprio(0);                                               \
    BARRIER();                                                                   \
    /* P2: read B1; Q01; read A-hi; drain lgkm (R fully read by this wave) */    \
    READ_B(rB1, RB_, 1);                                                         \
    __builtin_amdgcn_s_setprio(1);                                               \
    MFMA_Q(0, 1, rB1);                                                           \
    __builtin_amdgcn_s_setprio(0);                                               \
    READ_A(RB_, 1);                                                              \
    asm volatile("s_waitcnt lgkmcnt(0)" ::: "memory");                           \
    BARRIER();   /* all waves' reads from RB_ complete -> RB_ writable */        \
    /* P3: stage A(t+2) into RB_; Q10 */                                         \
    STAGE(pA, 0,   (RB_) + 0,     KA_);                                          \
    STAGE(pA, 128, (RB_) + 16384, KA_);                                          \
    __builtin_amdgcn_s_setprio(1);                                               \
    MFMA_Q(1, 0, rB0);                                                           \
    __builtin_amdgcn_s_setprio(0);                                               \
    BARRIER();                                                                   \
    /* P4: Q11; gate (leaves only A(t+2) in flight); certify tile t+1 */         \
    __builtin_amdgcn_s_setprio(1);                                               \
    MFMA_Q(1, 1, rB1);                                                           \
    __builtin_amdgcn_s_setprio(0);                                               \
    asm volatile("s_waitcnt vmcnt(4)" ::: "memory");                             \
    BARRIER();                                                                   \
} while (0)

    // prologue: tile0 (all 4 half-tiles) + A half-tiles of tile1 ("P3(-1)")
    STAGE(pA, 0,   0,             0);    // A-lo(0) -> buf0
    STAGE(pA, 128, 16384,         0);    // A-hi(0)
    STAGE(pB, 0,   32768,         0);    // B-lo(0)
    STAGE(pB, 128, 49152,         0);    // B-hi(0)
    STAGE(pA, 0,   65536 + 0,     64);   // A-lo(1) -> buf1
    STAGE(pA, 128, 65536 + 16384, 64);   // A-hi(1)
    asm volatile("s_waitcnt vmcnt(4)" ::: "memory");  // tile0 landed, A(1) in flight
    BARRIER();

#pragma unroll 1
    for (int it = 0; it < 32; ++it) {
        const int tt = 2 * it;
        const int kB0 = ((tt + 1) & 63) * 64;   // B of tile tt+1
        const int kA0 = ((tt + 2) & 63) * 64;   // A of tile tt+2
        const int kB1 = ((tt + 2) & 63) * 64;   // B of tile tt+2
        const int kA1 = ((tt + 3) & 63) * 64;   // A of tile tt+3
        TILE(0,     65536, kB0, kA0);
        TILE(65536, 0,     kB1, kA1);
    }
    asm volatile("s_waitcnt vmcnt(0)" ::: "memory"); // drain dangling prefetch

#undef TILE
#undef MFMA_Q
#undef READ_B
#undef READ_A
#undef STAGE
#undef BARRIER

    // epilogue: C/D layout row = quad*4 + v, col = r16
    float bj[4];
#pragma unroll
    for (int j = 0; j < 4; ++j) bj[j] = bias[n0 + wc * 64 + j * 16 + r16];

#pragma unroll
    for (int mf = 0; mf < 8; ++mf) {
        const int mrow = m0 + wr * 128 + mf * 16 + quad * 4;
#pragma unroll
        for (int nf = 0; nf < 4; ++nf) {
            const int n = n0 + wc * 64 + nf * 16 + r16;
#pragma unroll
            for (int v = 0; v < 4; ++v)
                out[(size_t)(mrow + v) * OUT_F + n] = acc[mf][nf][v] + bj[nf];
        }
    }
}

// ---------------- fused fallback (only if workspace too small) ----------------
__global__ __launch_bounds__(256) void palett_gemm_fused(
    const float* __restrict__ Af,             // [M][K] fp32
    const int* __restrict__ Widx,             // [N][K] int32
    const float* __restrict__ lut,
    const float* __restrict__ bias,
    float* __restrict__ out)
{
    __shared__ __align__(16) unsigned short smA[128 * 32];
    __shared__ __align__(16) unsigned short smB[128 * 32];
    __shared__ float slut[256];

    const int t    = threadIdx.x;
    const int w    = t >> 6;
    const int l    = t & 63;
    const int quad = l >> 4;
    const int r16  = l & 15;
    const int wr   = w >> 1;
    const int wc   = w & 1;

    const int m0 = blockIdx.y * 128;
    const int n0 = blockIdx.x * 128;

    const int g0  = t * 8;
    const int row = g0 >> 5;
    const int col = g0 & 31;

    char* const smA_c = (char*)smA;
    char* const smB_c = (char*)smB;

    slut[t] = lut[t];
    __syncthreads();

    uint32_t aoff[4], boff[4];
#pragma unroll
    for (int i = 0; i < 4; ++i) {
        aoff[i] = (uint32_t)(((wr * 64 + i * 16 + r16) * 32 + quad * 8) * 2);
        boff[i] = (uint32_t)(((wc * 64 + i * 16 + r16) * 32 + quad * 8) * 2);
    }

    f32x4 acc[4][4] = {};

    const float* af0 = Af + (size_t)(m0 + row) * IN_F + col;
    const float* af1 = Af + (size_t)(m0 + row + 64) * IN_F + col;
    const int*   wi0 = Widx + (size_t)(n0 + row) * IN_F + col;
    const int*   wi1 = Widx + (size_t)(n0 + row + 64) * IN_F + col;

    for (int k0 = 0; k0 < IN_F; k0 += 32) {
        float4 x0 = *(const float4*)(af0 + k0);
        float4 x1 = *(const float4*)(af0 + k0 + 4);
        uint4 p;
        p.x = pack_bf16x2(x0.x, x0.y); p.y = pack_bf16x2(x0.z, x0.w);
        p.z = pack_bf16x2(x1.x, x1.y); p.w = pack_bf16x2(x1.z, x1.w);
        *(uint4*)(smA_c + t * 16) = p;
        x0 = *(const float4*)(af1 + k0);
        x1 = *(const float4*)(af1 + k0 + 4);
        p.x = pack_bf16x2(x0.x, x0.y); p.y = pack_bf16x2(x0.z, x0.w);
        p.z = pack_bf16x2(x1.x, x1.y); p.w = pack_bf16x2(x1.z, x1.w);
        *(uint4*)(smA_c + 4096 + t * 16) = p;

        int4 j0 = *(const int4*)(wi0 + k0);
        int4 j1 = *(const int4*)(wi0 + k0 + 4);
        p.x = pack_bf16x2(slut[j0.x], slut[j0.y]);
        p.y = pack_bf16x2(slut[j0.z], slut[j0.w]);
        p.z = pack_bf16x2(slut[j1.x], slut[j1.y]);
        p.w = pack_bf16x2(slut[j1.z], slut[j1.w]);
        *(uint4*)(smB_c + t * 16) = p;
        j0 = *(const int4*)(wi1 + k0);
        j1 = *(const int4*)(wi1 + k0 + 4);
        p.x = pack_bf16x2(slut[j0.x], slut[j0.y]);
        p.y = pack_bf16x2(slut[j0.z], slut[j0.w]);
        p.z = pack_bf16x2(slut[j1.x], slut[j1.y]);
        p.w = pack_bf16x2(slut[j1.z], slut[j1.w]);
        *(uint4*)(smB_c + 4096 + t * 16) = p;
        __syncthreads();

        bf16x8 afr[4], bfr[4];
#pragma unroll
        for (int i = 0; i < 4; ++i) afr[i] = *(const bf16x8*)(smA_c + aoff[i]);
#pragma unroll
        for (int j = 0; j < 4; ++j) bfr[j] = *(const bf16x8*)(smB_c + boff[j]);
#pragma unroll
        for (int i = 0; i < 4; ++i)
#pragma unroll
            for (int j = 0; j < 4; ++j)
                acc[i][j] = __builtin_amdgcn_mfma_f32_16x16x32_bf16(
                    afr[i], bfr[j], acc[i][j], 0, 0, 0);
        __syncthreads();
    }

    float bj[4];
#pragma unroll
    for (int j = 0; j < 4; ++j) bj[j] = bias[n0 + wc * 64 + j * 16 + r16];

#pragma unroll
    for (int i = 0; i < 4; ++i) {
        const int mbase = m0 + wr * 64 + i * 16 + quad * 4;
#pragma unroll
        for (int j = 0; j < 4; ++j) {
            const int n = n0 + wc * 64 + j * 16 + r16;
#pragma unroll
            for (int v = 0; v < 4; ++v) {
                out[(size_t)(mbase + v) * OUT_F + n] = acc[i][j][v] + bj[j];
            }
        }
    }
}

extern "C" void kernel_launch(void* const* d_in, const int* in_sizes, int n_in,
                              void* d_out, int out_size, void* d_ws, size_t ws_size,
                              hipStream_t stream) {
    const float* input = (const float*)d_in[0];   // [8192][4096] fp32
    const int*   widx  = (const int*)d_in[1];     // [16384][4096] int32
    const float* lut   = (const float*)d_in[2];   // [256] fp32
    const float* bias  = (const float*)d_in[3];   // [16384] fp32
    float* out = (float*)d_out;                   // [8192][16384] fp32

    const size_t aBytes = (size_t)TOKENS * IN_F * sizeof(unsigned short); //  64 MB
    const size_t bBytes = (size_t)OUT_F  * IN_F * sizeof(unsigned short); // 128 MB

    if (ws_size >= aBytes + bBytes) {
        unsigned short* wsA = (unsigned short*)d_ws;
        unsigned short* wsB = (unsigned short*)((char*)d_ws + aBytes);
        const int nA8 = (TOKENS * IN_F) / 8;
        const int nB8 = (OUT_F  * IN_F) / 8;
        cvt_input_kernel<<<(nA8 + 255) / 256, 256, 0, stream>>>(input, wsA, nA8);
        dequant_kernel<<<(nB8 + 255) / 256, 256, 0, stream>>>(widx, lut, wsB, nB8);
        dim3 grid2(OUT_F / 256, TOKENS / 256);    // (64, 32) = 2048 blocks
        palett_gemm256<<<grid2, 512, 0, stream>>>(wsA, wsB, bias, out);
    } else {
        dim3 grid(OUT_F / 128, TOKENS / 128);
        palett_gemm_fused<<<grid, 256, 0, stream>>>(input, widx, lut, bias, out);
    }
}